// Round 1
// baseline (144.152 us; speedup 1.0000x reference)
//
#include <hip/hip_runtime.h>

#define IMG   128
#define KF    4
#define NF    800
#define NV    2000
#define NB    2
#define EPSF  1e-8f
#define BLURF 0.01f

// Match numpy: no FMA contraction anywhere on the exact paths.
#pragma clang fp contract(off)

__device__ __forceinline__ float seg_d2(float pax, float pay, float abx, float aby) {
#pragma clang fp contract(off)
    // numpy: t = clip((pa.ab)/(ab.ab + EPS), 0, 1); d = pa - t*ab; return d.d
    float dd = (abx * abx + aby * aby) + EPSF;
    float t  = (pax * abx + pay * aby) / dd;   // true IEEE divide
    t = fminf(fmaxf(t, 0.0f), 1.0f);
    float dx = pax - t * abx;
    float dy = pay - t * aby;
    return dx * dx + dy * dy;
}

__global__ __launch_bounds__(512, 4) void raster_kernel(
    const float* __restrict__ verts,   // (B, V, 3)
    const int*   __restrict__ faces,   // (F, 3)
    float* __restrict__ out0,          // pix_to_face as float (B,H,W,K)
    float* __restrict__ out1,          // zbuf
    float* __restrict__ out2,          // bary (B,H,W,K,3)
    float* __restrict__ out3)          // dsign
{
#pragma clang fp contract(off)
    __shared__ float4 sBB[NF];          // expanded bbox: xmin,xmax,ymin,ymax
    __shared__ float  sFD[NF * 10];     // a0x,a0y,a1x,a1y,a2x,a2y,z0,z1,z2,denom
    __shared__ float  sCZ[8 * 64 * 4];  // per-chunk top4 z
    __shared__ int    sCI[8 * 64 * 4];  // per-chunk top4 idx

    const float FINF = __builtin_inff();
    const int tid  = threadIdx.x;
    const int blk  = blockIdx.x;            // 0..511
    const int b    = blk >> 8;              // batch
    const int trow = (blk & 255) >> 4;      // tile row 0..15
    const int tcol = blk & 15;              // tile col 0..15
    const float* vb = verts + b * NV * 3;

    // ---------------- staging: per-face data -> LDS ----------------
    for (int f = tid; f < NF; f += 512) {
        int i0 = faces[3 * f + 0], i1 = faces[3 * f + 1], i2 = faces[3 * f + 2];
        float a0x = vb[3 * i0], a0y = vb[3 * i0 + 1], z0 = vb[3 * i0 + 2];
        float a1x = vb[3 * i1], a1y = vb[3 * i1 + 1], z1 = vb[3 * i1 + 2];
        float a2x = vb[3 * i2], a2y = vb[3 * i2 + 1], z2 = vb[3 * i2 + 2];
        // numpy op order for area (exact-match)
        float area = (a2x - a0x) * (a1y - a0y) - (a2y - a0y) * (a1x - a0x);
        float aab  = fabsf(area);
        float denom = (aab > EPSF) ? area : (area >= 0.0f ? EPSF : -EPSF);
        float4 bb;
        if (aab > EPSF) {
            // expand by sqrt(BLUR)=0.1 (+margin): outside => dmin>BLUR and not inside
            bb.x = fminf(a0x, fminf(a1x, a2x)) - 0.101f;
            bb.y = fmaxf(a0x, fmaxf(a1x, a2x)) + 0.101f;
            bb.z = fminf(a0y, fminf(a1y, a2y)) - 0.101f;
            bb.w = fmaxf(a0y, fmaxf(a1y, a2y)) + 0.101f;
        } else {
            // degenerate area => never valid => empty bbox so every wave skips it
            bb.x = 1e30f; bb.y = -1e30f; bb.z = 1e30f; bb.w = -1e30f;
        }
        sBB[f] = bb;
        float* fd = &sFD[f * 10];
        fd[0] = a0x; fd[1] = a0y; fd[2] = a1x; fd[3] = a1y; fd[4] = a2x; fd[5] = a2y;
        fd[6] = z0;  fd[7] = z1;  fd[8] = z2;  fd[9] = denom;
    }
    __syncthreads();

    // ---------------- phase 1: per-wave top-4 over its face chunk ----------------
    const int wave = tid >> 6;
    const int lane = tid & 63;
    const int pr = lane >> 3, pc = lane & 7;          // 8x8 tile
    const int row = trow * 8 + pr, col = tcol * 8 + pc;
    // exact numpy pixel centers (all values exact in f32)
    const float px = 1.0f - (2.0f * ((float)col + 0.5f)) / 128.0f;
    const float py = 1.0f - (2.0f * ((float)row + 0.5f)) / 128.0f;
    // tile pixel-center bounds (x,y decrease with col,row)
    const float txmax = 1.0f - (2.0f * ((float)(tcol * 8)     + 0.5f)) / 128.0f;
    const float txmin = 1.0f - (2.0f * ((float)(tcol * 8 + 7) + 0.5f)) / 128.0f;
    const float tymax = 1.0f - (2.0f * ((float)(trow * 8)     + 0.5f)) / 128.0f;
    const float tymin = 1.0f - (2.0f * ((float)(trow * 8 + 7) + 0.5f)) / 128.0f;

    float s0z = FINF, s1z = FINF, s2z = FINF, s3z = FINF;
    int   s0i = -1,   s1i = -1,   s2i = -1,   s3i = -1;

    const int f0 = wave * 100, f1 = f0 + 100;
    for (int f = f0; f < f1; ++f) {
        float4 bb = sBB[f];   // wave-uniform broadcast
        if (bb.x > txmax || bb.y < txmin || bb.z > tymax || bb.w < tymin) continue;
        const float* fd = &sFD[f * 10];
        float a0x = fd[0], a0y = fd[1], a1x = fd[2], a1y = fd[3], a2x = fd[4], a2y = fd[5];
        float z0 = fd[6], z1 = fd[7], z2 = fd[8], denom = fd[9];
        float e0x = a2x - a1x, e0y = a2y - a1y;   // a1->a2
        float e1x = a0x - a2x, e1y = a0y - a2y;   // a2->a0
        float e2x = a1x - a0x, e2y = a1y - a0y;   // a0->a1
        float p0x = px - a0x, p0y = py - a0y;
        float p1x = px - a1x, p1y = py - a1y;
        float p2x = px - a2x, p2y = py - a2y;
        float w0 = p1x * e0y - p1y * e0x;
        float w1 = p2x * e1y - p2y * e1x;
        float w2 = p0x * e2y - p0y * e2x;
        float b0 = w0 / denom, b1 = w1 / denom, b2 = w2 / denom;  // IEEE divides
        float zpix = (b0 * z0 + b1 * z1) + b2 * z2;               // numpy order
        bool inside = (b0 >= 0.0f) & (b1 >= 0.0f) & (b2 >= 0.0f);
        float dA = seg_d2(p0x, p0y, e2x, e2y);   // (p,a0,a1)
        float dB = seg_d2(p1x, p1y, e0x, e0y);   // (p,a1,a2)
        float dC = seg_d2(p2x, p2y, e1x, e1y);   // (p,a2,a0)
        float dmin = fminf(dA, fminf(dB, dC));
        bool valid = (inside | (dmin < BLURF)) & (zpix > EPSF);
        float zc = valid ? zpix : FINF;
        if (__any(zc < s3z)) {
            bool c0 = zc < s0z, c1 = zc < s1z, c2 = zc < s2z, c3 = zc < s3z;
            s3z = c2 ? s2z : (c3 ? zc : s3z); s3i = c2 ? s2i : (c3 ? f : s3i);
            s2z = c1 ? s1z : (c2 ? zc : s2z); s2i = c1 ? s1i : (c2 ? f : s2i);
            s1z = c0 ? s0z : (c1 ? zc : s1z); s1i = c0 ? s0i : (c1 ? f : s1i);
            s0z = c0 ? zc  : s0z;             s0i = c0 ? f   : s0i;
        }
    }
    {
        int cb = (wave * 64 + lane) * 4;
        sCZ[cb + 0] = s0z; sCZ[cb + 1] = s1z; sCZ[cb + 2] = s2z; sCZ[cb + 3] = s3z;
        sCI[cb + 0] = s0i; sCI[cb + 1] = s1i; sCI[cb + 2] = s2i; sCI[cb + 3] = s3i;
    }
    __syncthreads();

    // ---------------- merge: 8 chunks x 4 -> global top-4 (tie: lower idx) -------
    if (tid < 64) {
        float m0 = FINF, m1 = FINF, m2 = FINF, m3 = FINF;
        int   j0 = -1,   j1 = -1,   j2 = -1,   j3 = -1;
        for (int w = 0; w < 8; ++w) {        // ascending chunk == ascending idx
            int base = (w * 64 + tid) * 4;
            for (int k = 0; k < 4; ++k) {
                float zc = sCZ[base + k];
                int   fi = sCI[base + k];
                bool c0 = zc < m0, c1 = zc < m1, c2 = zc < m2, c3 = zc < m3;
                m3 = c2 ? m2 : (c3 ? zc : m3); j3 = c2 ? j2 : (c3 ? fi : j3);
                m2 = c1 ? m1 : (c2 ? zc : m2); j2 = c1 ? j1 : (c2 ? fi : j2);
                m1 = c0 ? m0 : (c1 ? zc : m1); j1 = c0 ? j0 : (c1 ? fi : j1);
                m0 = c0 ? zc : m0;             j0 = c0 ? fi : j0;
            }
        }
        int b0i = tid * 4;   // reuse chunk-0 rows (only this thread touches them)
        sCZ[b0i + 0] = m0; sCZ[b0i + 1] = m1; sCZ[b0i + 2] = m2; sCZ[b0i + 3] = m3;
        sCI[b0i + 0] = j0; sCI[b0i + 1] = j1; sCI[b0i + 2] = j2; sCI[b0i + 3] = j3;
    }
    __syncthreads();

    // ---------------- phase 2: exact recompute for <=4 selected, write ----------
    if (tid < 256) {
        int pix = tid >> 2, k = tid & 3;
        int fi = sCI[pix * 4 + k];
        int prow = pix >> 3, pcol = pix & 7;
        int grow = trow * 8 + prow, gcol = tcol * 8 + pcol;
        int p = (b * IMG + grow) * IMG + gcol;
        float qx = 1.0f - (2.0f * ((float)gcol + 0.5f)) / 128.0f;
        float qy = 1.0f - (2.0f * ((float)grow + 0.5f)) / 128.0f;
        float o0 = -1.0f, o1 = -1.0f, ob0 = -1.0f, ob1 = -1.0f, ob2 = -1.0f, o3 = -1.0f;
        if (fi >= 0) {
            const float* fd = &sFD[fi * 10];
            float a0x = fd[0], a0y = fd[1], a1x = fd[2], a1y = fd[3], a2x = fd[4], a2y = fd[5];
            float z0 = fd[6], z1 = fd[7], z2 = fd[8], denom = fd[9];
            float e0x = a2x - a1x, e0y = a2y - a1y;
            float e1x = a0x - a2x, e1y = a0y - a2y;
            float e2x = a1x - a0x, e2y = a1y - a0y;
            float p0x = qx - a0x, p0y = qy - a0y;
            float p1x = qx - a1x, p1y = qy - a1y;
            float p2x = qx - a2x, p2y = qy - a2y;
            float w0 = p1x * e0y - p1y * e0x;
            float w1 = p2x * e1y - p2y * e1x;
            float w2 = p0x * e2y - p0y * e2x;
            float b0 = w0 / denom, b1 = w1 / denom, b2 = w2 / denom;
            float zpix = (b0 * z0 + b1 * z1) + b2 * z2;
            bool inside = (b0 >= 0.0f) & (b1 >= 0.0f) & (b2 >= 0.0f);
            float dA = seg_d2(p0x, p0y, e2x, e2y);
            float dB = seg_d2(p1x, p1y, e0x, e0y);
            float dC = seg_d2(p2x, p2y, e1x, e1y);
            float dmin = fminf(dA, fminf(dB, dC));
            o0 = (float)fi;
            o1 = zpix;
            ob0 = b0; ob1 = b1; ob2 = b2;
            o3 = inside ? -dmin : dmin;
        }
        int o = p * KF + k;
        out0[o] = o0;
        out1[o] = o1;
        out2[o * 3 + 0] = ob0;
        out2[o * 3 + 1] = ob1;
        out2[o * 3 + 2] = ob2;
        out3[o] = o3;
    }
}

extern "C" void kernel_launch(void* const* d_in, const int* in_sizes, int n_in,
                              void* d_out, int out_size, void* d_ws, size_t ws_size,
                              hipStream_t stream) {
    const float* verts = (const float*)d_in[0];
    const int*   faces = (const int*)d_in[1];
    float* out = (float*)d_out;
    const int n0 = NB * IMG * IMG * KF;   // 131072 per (B,H,W,K) output
    // concat order: pix_to_face, zbuf, bary(3x), dsign
    raster_kernel<<<dim3(512), dim3(512), 0, stream>>>(
        verts, faces,
        out,                 // [0, n0)
        out + n0,            // [n0, 2n0)
        out + 2 * n0,        // [2n0, 5n0)
        out + 5 * n0);       // [5n0, 6n0)
}

// Round 2
// 110.213 us; speedup vs baseline: 1.3079x; 1.3079x over previous
//
#include <hip/hip_runtime.h>

#define IMG   128
#define KF    4
#define NF    800
#define NV    2000
#define NB    2
#define EPSF  1e-8f
#define BLURF 0.01f
#define CHUNK 100
// cull threshold: sqrt(BLUR)=0.1 + tile half-diagonal 0.0774 + margin -> 0.1785; squared:
#define CULL_T2 0.03186f

// Match numpy: no FMA contraction anywhere on the exact paths.
#pragma clang fp contract(off)

__device__ __forceinline__ float seg_d2(float pax, float pay, float abx, float aby) {
#pragma clang fp contract(off)
    float dd = (abx * abx + aby * aby) + EPSF;
    float t  = (pax * abx + pay * aby) / dd;   // true IEEE divide
    t = fminf(fmaxf(t, 0.0f), 1.0f);
    float dx = pax - t * abx;
    float dy = pay - t * aby;
    return dx * dx + dy * dy;
}

__global__ __launch_bounds__(512, 4) void raster_kernel(
    const float* __restrict__ verts,   // (B, V, 3)
    const int*   __restrict__ faces,   // (F, 3)
    float* __restrict__ out0,          // pix_to_face as float (B,H,W,K)
    float* __restrict__ out1,          // zbuf
    float* __restrict__ out2,          // bary (B,H,W,K,3)
    float* __restrict__ out3)          // dsign
{
#pragma clang fp contract(off)
    __shared__ float sFD[NF * 10];      // a0x,a0y,a1x,a1y,a2x,a2y,z0,z1,z2,denom
    __shared__ int   sList[NF];         // per-wave survivor lists [w*CHUNK, w*CHUNK+cnt)
    __shared__ float sCZ[8 * 64 * 4];   // per-chunk top4 z
    __shared__ int   sCI[8 * 64 * 4];   // per-chunk top4 idx

    const float FINF = __builtin_inff();
    const int tid  = threadIdx.x;
    const int blk  = blockIdx.x;            // 0..511
    const int b    = blk >> 8;              // batch
    const int trow = (blk & 255) >> 4;      // tile row 0..15
    const int tcol = blk & 15;              // tile col 0..15
    const float* vb = verts + b * NV * 3;

    // ---------------- staging: per-face data -> LDS ----------------
    for (int f = tid; f < NF; f += 512) {
        int i0 = faces[3 * f + 0], i1 = faces[3 * f + 1], i2 = faces[3 * f + 2];
        float a0x = vb[3 * i0], a0y = vb[3 * i0 + 1], z0 = vb[3 * i0 + 2];
        float a1x = vb[3 * i1], a1y = vb[3 * i1 + 1], z1 = vb[3 * i1 + 2];
        float a2x = vb[3 * i2], a2y = vb[3 * i2 + 1], z2 = vb[3 * i2 + 2];
        // numpy op order for area (exact-match)
        float area = (a2x - a0x) * (a1y - a0y) - (a2y - a0y) * (a1x - a0x);
        float aab  = fabsf(area);
        float denom = (aab > EPSF) ? area : (area >= 0.0f ? EPSF : -EPSF);
        float* fd = &sFD[f * 10];
        fd[0] = a0x; fd[1] = a0y; fd[2] = a1x; fd[3] = a1y; fd[4] = a2x; fd[5] = a2y;
        fd[6] = z0;  fd[7] = z1;  fd[8] = z2;  fd[9] = denom;
    }
    __syncthreads();

    // ---------------- geometry (wave-uniform tile, per-lane pixel) ----------------
    const int wave = tid >> 6;
    const int lane = tid & 63;
    const int pr = lane >> 3, pc = lane & 7;          // 8x8 tile
    const int row = trow * 8 + pr, col = tcol * 8 + pc;
    const float px = 1.0f - (2.0f * ((float)col + 0.5f)) / 128.0f;
    const float py = 1.0f - (2.0f * ((float)row + 0.5f)) / 128.0f;
    // tile pixel-center bounds (x,y decrease with col,row)
    const float txmax = 1.0f - (2.0f * ((float)(tcol * 8)     + 0.5f)) / 128.0f;
    const float txmin = 1.0f - (2.0f * ((float)(tcol * 8 + 7) + 0.5f)) / 128.0f;
    const float tymax = 1.0f - (2.0f * ((float)(trow * 8)     + 0.5f)) / 128.0f;
    const float tymin = 1.0f - (2.0f * ((float)(trow * 8 + 7) + 0.5f)) / 128.0f;
    const float cx = 0.5f * (txmin + txmax);
    const float cy = 0.5f * (tymin + tymax);

    // ---------------- cull + ordered compaction (per-wave chunk) ----------------
    const int f0 = wave * CHUNK;
    int cnt = 0;
    for (int it = 0; it < 2; ++it) {
        int f = f0 + it * 64 + lane;
        bool surv = false;
        if (f < f0 + CHUNK) {
            const float* fd = &sFD[f * 10];
            float a0x = fd[0], a0y = fd[1], a1x = fd[2], a1y = fd[3], a2x = fd[4], a2y = fd[5];
            float area = (a2x - a0x) * (a1y - a0y) - (a2y - a0y) * (a1x - a0x);
            surv = fabsf(area) > EPSF;
            // bbox cull (handles corner wedges)
            float bxmin = fminf(a0x, fminf(a1x, a2x)) - 0.101f;
            float bxmax = fmaxf(a0x, fmaxf(a1x, a2x)) + 0.101f;
            float bymin = fminf(a0y, fminf(a1y, a2y)) - 0.101f;
            float bymax = fmaxf(a0y, fmaxf(a1y, a2y)) + 0.101f;
            surv &= !(bxmin > txmax || bxmax < txmin || bymin > tymax || bymax < tymin);
            // per-edge half-plane cull: tile center entirely outside an edge line
            // by > 0.1785 (blur 0.1 + tile half-diag + margin) => invalid for all pixels
            float s = (area >= 0.0f) ? 1.0f : -1.0f;
            float e0x = a2x - a1x, e0y = a2y - a1y;   // a1->a2
            float e1x = a0x - a2x, e1y = a0y - a2y;   // a2->a0
            float e2x = a1x - a0x, e2y = a1y - a0y;   // a0->a1
            float w0 = s * ((cx - a1x) * e0y - (cy - a1y) * e0x);
            float w1 = s * ((cx - a2x) * e1y - (cy - a2y) * e1x);
            float w2 = s * ((cx - a0x) * e2y - (cy - a0y) * e2x);
            float l0 = e0x * e0x + e0y * e0y;
            float l1 = e1x * e1x + e1y * e1y;
            float l2 = e2x * e2x + e2y * e2y;
            surv &= !((w0 < 0.0f) & (w0 * w0 > CULL_T2 * l0));
            surv &= !((w1 < 0.0f) & (w1 * w1 > CULL_T2 * l1));
            surv &= !((w2 < 0.0f) & (w2 * w2 > CULL_T2 * l2));
        }
        unsigned long long m = __ballot(surv);
        if (surv) {
            int pos = __popcll(m & ((1ull << lane) - 1ull));
            sList[f0 + cnt + pos] = f;   // ascending index order preserved
        }
        cnt += __popcll(m);
    }

    // ---------------- phase 1: per-wave top-4 over survivor list ----------------
    float s0z = FINF, s1z = FINF, s2z = FINF, s3z = FINF;
    int   s0i = -1,   s1i = -1,   s2i = -1,   s3i = -1;

    for (int j = 0; j < cnt; ++j) {
        int f = sList[f0 + j];                 // wave-uniform broadcast
        const float* fd = &sFD[f * 10];
        float a0x = fd[0], a0y = fd[1], a1x = fd[2], a1y = fd[3], a2x = fd[4], a2y = fd[5];
        float z0 = fd[6], z1 = fd[7], z2 = fd[8], denom = fd[9];
        float e0x = a2x - a1x, e0y = a2y - a1y;   // a1->a2
        float e1x = a0x - a2x, e1y = a0y - a2y;   // a2->a0
        float e2x = a1x - a0x, e2y = a1y - a0y;   // a0->a1
        float p0x = px - a0x, p0y = py - a0y;
        float p1x = px - a1x, p1y = py - a1y;
        float p2x = px - a2x, p2y = py - a2y;
        float w0 = p1x * e0y - p1y * e0x;
        float w1 = p2x * e1y - p2y * e1x;
        float w2 = p0x * e2y - p0y * e2x;
        float b0 = w0 / denom, b1 = w1 / denom, b2 = w2 / denom;  // IEEE divides
        float zpix = (b0 * z0 + b1 * z1) + b2 * z2;               // numpy order
        bool inside = fminf(b0, fminf(b1, b2)) >= 0.0f;           // no NaNs possible
        bool valid;
        if (__all(inside)) {
            // inside => (inside | dmin<blur) true; dmin irrelevant for phase 1
            valid = (zpix > EPSF);
        } else {
            float dA = seg_d2(p0x, p0y, e2x, e2y);   // (p,a0,a1)
            float dB = seg_d2(p1x, p1y, e0x, e0y);   // (p,a1,a2)
            float dC = seg_d2(p2x, p2y, e1x, e1y);   // (p,a2,a0)
            float dmin = fminf(dA, fminf(dB, dC));
            valid = (inside | (dmin < BLURF)) & (zpix > EPSF);
        }
        float zc = valid ? zpix : FINF;
        if (__any(zc < s3z)) {
            bool c0 = zc < s0z, c1 = zc < s1z, c2 = zc < s2z, c3 = zc < s3z;
            s3z = c2 ? s2z : (c3 ? zc : s3z); s3i = c2 ? s2i : (c3 ? f : s3i);
            s2z = c1 ? s1z : (c2 ? zc : s2z); s2i = c1 ? s1i : (c2 ? f : s2i);
            s1z = c0 ? s0z : (c1 ? zc : s1z); s1i = c0 ? s0i : (c1 ? f : s1i);
            s0z = c0 ? zc  : s0z;             s0i = c0 ? f   : s0i;
        }
    }
    {
        int cb = (wave * 64 + lane) * 4;
        sCZ[cb + 0] = s0z; sCZ[cb + 1] = s1z; sCZ[cb + 2] = s2z; sCZ[cb + 3] = s3z;
        sCI[cb + 0] = s0i; sCI[cb + 1] = s1i; sCI[cb + 2] = s2i; sCI[cb + 3] = s3i;
    }
    __syncthreads();

    // ---------------- merge: 8 chunks x 4 -> global top-4 (tie: lower idx) -------
    if (tid < 64) {
        float m0 = FINF, m1 = FINF, m2 = FINF, m3 = FINF;
        int   j0 = -1,   j1 = -1,   j2 = -1,   j3 = -1;
        for (int w = 0; w < 8; ++w) {        // ascending chunk == ascending idx
            int base = (w * 64 + tid) * 4;
            for (int k = 0; k < 4; ++k) {
                float zc = sCZ[base + k];
                int   fi = sCI[base + k];
                bool c0 = zc < m0, c1 = zc < m1, c2 = zc < m2, c3 = zc < m3;
                m3 = c2 ? m2 : (c3 ? zc : m3); j3 = c2 ? j2 : (c3 ? fi : j3);
                m2 = c1 ? m1 : (c2 ? zc : m2); j2 = c1 ? j1 : (c2 ? fi : j2);
                m1 = c0 ? m0 : (c1 ? zc : m1); j1 = c0 ? j0 : (c1 ? fi : j1);
                m0 = c0 ? zc : m0;             j0 = c0 ? fi : j0;
            }
        }
        int b0i = tid * 4;   // reuse chunk-0 rows (only this thread touches them)
        sCZ[b0i + 0] = m0; sCZ[b0i + 1] = m1; sCZ[b0i + 2] = m2; sCZ[b0i + 3] = m3;
        sCI[b0i + 0] = j0; sCI[b0i + 1] = j1; sCI[b0i + 2] = j2; sCI[b0i + 3] = j3;
    }
    __syncthreads();

    // ---------------- phase 2: exact recompute for <=4 selected, write ----------
    if (tid < 256) {
        int pix = tid >> 2, k = tid & 3;
        int fi = sCI[pix * 4 + k];
        int prow = pix >> 3, pcol = pix & 7;
        int grow = trow * 8 + prow, gcol = tcol * 8 + pcol;
        int p = (b * IMG + grow) * IMG + gcol;
        float qx = 1.0f - (2.0f * ((float)gcol + 0.5f)) / 128.0f;
        float qy = 1.0f - (2.0f * ((float)grow + 0.5f)) / 128.0f;
        float o0 = -1.0f, o1 = -1.0f, ob0 = -1.0f, ob1 = -1.0f, ob2 = -1.0f, o3 = -1.0f;
        if (fi >= 0) {
            const float* fd = &sFD[fi * 10];
            float a0x = fd[0], a0y = fd[1], a1x = fd[2], a1y = fd[3], a2x = fd[4], a2y = fd[5];
            float z0 = fd[6], z1 = fd[7], z2 = fd[8], denom = fd[9];
            float e0x = a2x - a1x, e0y = a2y - a1y;
            float e1x = a0x - a2x, e1y = a0y - a2y;
            float e2x = a1x - a0x, e2y = a1y - a0y;
            float p0x = qx - a0x, p0y = qy - a0y;
            float p1x = qx - a1x, p1y = qy - a1y;
            float p2x = qx - a2x, p2y = qy - a2y;
            float w0 = p1x * e0y - p1y * e0x;
            float w1 = p2x * e1y - p2y * e1x;
            float w2 = p0x * e2y - p0y * e2x;
            float b0 = w0 / denom, b1 = w1 / denom, b2 = w2 / denom;
            float zpix = (b0 * z0 + b1 * z1) + b2 * z2;
            bool inside = (b0 >= 0.0f) & (b1 >= 0.0f) & (b2 >= 0.0f);
            float dA = seg_d2(p0x, p0y, e2x, e2y);
            float dB = seg_d2(p1x, p1y, e0x, e0y);
            float dC = seg_d2(p2x, p2y, e1x, e1y);
            float dmin = fminf(dA, fminf(dB, dC));
            o0 = (float)fi;
            o1 = zpix;
            ob0 = b0; ob1 = b1; ob2 = b2;
            o3 = inside ? -dmin : dmin;
        }
        int o = p * KF + k;
        out0[o] = o0;
        out1[o] = o1;
        out2[o * 3 + 0] = ob0;
        out2[o * 3 + 1] = ob1;
        out2[o * 3 + 2] = ob2;
        out3[o] = o3;
    }
}

extern "C" void kernel_launch(void* const* d_in, const int* in_sizes, int n_in,
                              void* d_out, int out_size, void* d_ws, size_t ws_size,
                              hipStream_t stream) {
    const float* verts = (const float*)d_in[0];
    const int*   faces = (const int*)d_in[1];
    float* out = (float*)d_out;
    const int n0 = NB * IMG * IMG * KF;   // 131072 per (B,H,W,K) output
    // concat order: pix_to_face, zbuf, bary(3x), dsign
    raster_kernel<<<dim3(512), dim3(512), 0, stream>>>(
        verts, faces,
        out,                 // [0, n0)
        out + n0,            // [n0, 2n0)
        out + 2 * n0,        // [2n0, 5n0)
        out + 5 * n0);       // [5n0, 6n0)
}

// Round 3
// 109.464 us; speedup vs baseline: 1.3169x; 1.0068x over previous
//
#include <hip/hip_runtime.h>

#define IMG   128
#define KF    4
#define NF    800
#define NV    2000
#define NB    2
#define EPSF  1e-8f
#define BLURF 0.01f
#define NW    16        // waves per block
#define CCH   50        // cull chunk per wave (16*50 = 800)
// cull threshold: sqrt(BLUR)=0.1 + tile half-diagonal 0.0774 + margin -> 0.1785; squared:
#define CULL_T2 0.03186f

typedef unsigned long long u64;
#define INVK ((((u64)0x7f800000u) << 32) | 0xffffffffu)   // z=+inf, idx=-1

// Match numpy: no FMA contraction anywhere on the exact paths.
#pragma clang fp contract(off)

__device__ __forceinline__ float seg_d2(float pax, float pay, float abx, float aby) {
#pragma clang fp contract(off)
    float dd = (abx * abx + aby * aby) + EPSF;
    float t  = (pax * abx + pay * aby) / dd;   // true IEEE divide
    t = fminf(fmaxf(t, 0.0f), 1.0f);
    float dx = pax - t * abx;
    float dy = pay - t * aby;
    return dx * dx + dy * dy;
}

__device__ __forceinline__ void ins4(u64& s0, u64& s1, u64& s2, u64& s3, u64 k) {
    bool c0 = k < s0, c1 = k < s1, c2 = k < s2, c3 = k < s3;
    s3 = c2 ? s2 : (c3 ? k : s3);
    s2 = c1 ? s1 : (c2 ? k : s2);
    s1 = c0 ? s0 : (c1 ? k : s1);
    s0 = c0 ? k  : s0;
}

__global__ __launch_bounds__(1024, 8) void raster_kernel(
    const float* __restrict__ verts,   // (B, V, 3)
    const int*   __restrict__ faces,   // (F, 3)
    float* __restrict__ out0,          // pix_to_face as float (B,H,W,K)
    float* __restrict__ out1,          // zbuf
    float* __restrict__ out2,          // bary (B,H,W,K,3)
    float* __restrict__ out3)          // dsign
{
#pragma clang fp contract(off)
    __shared__ float sFD[NF * 10];       // a0x,a0y,a1x,a1y,a2x,a2y,z0,z1,z2,denom
    __shared__ u64   sK[8 * 4 * 64];     // merge rows: [row][k][lane], conflict-free
    __shared__ int   sList[NF];          // shared survivor list
    __shared__ int   sCnt[NW];
    __shared__ int   sOff[NW];
    __shared__ int   sTot;

    const int tid  = threadIdx.x;
    const int blk  = blockIdx.x;            // 0..511
    const int b    = blk >> 8;              // batch
    const int trow = (blk & 255) >> 4;      // tile row 0..15
    const int tcol = blk & 15;              // tile col 0..15
    const float* vb = verts + b * NV * 3;

    // ---------------- staging: per-face data -> LDS ----------------
    if (tid < NF) {
        int f = tid;
        int i0 = faces[3 * f + 0], i1 = faces[3 * f + 1], i2 = faces[3 * f + 2];
        float a0x = vb[3 * i0], a0y = vb[3 * i0 + 1], z0 = vb[3 * i0 + 2];
        float a1x = vb[3 * i1], a1y = vb[3 * i1 + 1], z1 = vb[3 * i1 + 2];
        float a2x = vb[3 * i2], a2y = vb[3 * i2 + 1], z2 = vb[3 * i2 + 2];
        // numpy op order for area (exact-match)
        float area = (a2x - a0x) * (a1y - a0y) - (a2y - a0y) * (a1x - a0x);
        float aab  = fabsf(area);
        float denom = (aab > EPSF) ? area : (area >= 0.0f ? EPSF : -EPSF);
        float* fd = &sFD[f * 10];
        fd[0] = a0x; fd[1] = a0y; fd[2] = a1x; fd[3] = a1y; fd[4] = a2x; fd[5] = a2y;
        fd[6] = z0;  fd[7] = z1;  fd[8] = z2;  fd[9] = denom;
    }
    __syncthreads();

    // ---------------- geometry (wave-uniform tile, per-lane pixel) ----------------
    const int wave = tid >> 6;
    const int lane = tid & 63;
    const int pr = lane >> 3, pc = lane & 7;          // 8x8 tile
    const int row = trow * 8 + pr, col = tcol * 8 + pc;
    const float px = 1.0f - (2.0f * ((float)col + 0.5f)) / 128.0f;
    const float py = 1.0f - (2.0f * ((float)row + 0.5f)) / 128.0f;
    const float txmax = 1.0f - (2.0f * ((float)(tcol * 8)     + 0.5f)) / 128.0f;
    const float txmin = 1.0f - (2.0f * ((float)(tcol * 8 + 7) + 0.5f)) / 128.0f;
    const float tymax = 1.0f - (2.0f * ((float)(trow * 8)     + 0.5f)) / 128.0f;
    const float tymin = 1.0f - (2.0f * ((float)(trow * 8 + 7) + 0.5f)) / 128.0f;
    const float cx = 0.5f * (txmin + txmax);
    const float cy = 0.5f * (tymin + tymax);

    // ---------------- cooperative cull -> shared survivor list ----------------
    int fc = wave * CCH + lane;           // this thread's cull candidate
    bool surv = false;
    if (lane < CCH) {
        const float* fd = &sFD[fc * 10];
        float a0x = fd[0], a0y = fd[1], a1x = fd[2], a1y = fd[3], a2x = fd[4], a2y = fd[5];
        float area = (a2x - a0x) * (a1y - a0y) - (a2y - a0y) * (a1x - a0x);
        surv = fabsf(area) > EPSF;
        float bxmin = fminf(a0x, fminf(a1x, a2x)) - 0.101f;
        float bxmax = fmaxf(a0x, fmaxf(a1x, a2x)) + 0.101f;
        float bymin = fminf(a0y, fminf(a1y, a2y)) - 0.101f;
        float bymax = fmaxf(a0y, fmaxf(a1y, a2y)) + 0.101f;
        surv &= !(bxmin > txmax || bxmax < txmin || bymin > tymax || bymax < tymin);
        // per-edge half-plane cull vs tile center (conservative radius)
        float s = (area >= 0.0f) ? 1.0f : -1.0f;
        float e0x = a2x - a1x, e0y = a2y - a1y;
        float e1x = a0x - a2x, e1y = a0y - a2y;
        float e2x = a1x - a0x, e2y = a1y - a0y;
        float w0 = s * ((cx - a1x) * e0y - (cy - a1y) * e0x);
        float w1 = s * ((cx - a2x) * e1y - (cy - a2y) * e1x);
        float w2 = s * ((cx - a0x) * e2y - (cy - a0y) * e2x);
        float l0 = e0x * e0x + e0y * e0y;
        float l1 = e1x * e1x + e1y * e1y;
        float l2 = e2x * e2x + e2y * e2y;
        surv &= !((w0 < 0.0f) & (w0 * w0 > CULL_T2 * l0));
        surv &= !((w1 < 0.0f) & (w1 * w1 > CULL_T2 * l1));
        surv &= !((w2 < 0.0f) & (w2 * w2 > CULL_T2 * l2));
    }
    unsigned long long m = __ballot(surv);
    int pos = __popcll(m & ((1ull << lane) - 1ull));
    if (lane == 0) sCnt[wave] = __popcll(m);
    __syncthreads();
    if (tid == 0) {
        int r = 0;
        for (int w = 0; w < NW; ++w) { sOff[w] = r; r += sCnt[w]; }
        sTot = r;
    }
    __syncthreads();
    if (surv) sList[sOff[wave] + pos] = fc;
    int total = sTot;   // read before the list-write barrier is fine? no: sTot set above
    __syncthreads();

    // ---------------- phase 1: strided top-4 over shared survivor list ----------
    u64 s0 = INVK, s1 = INVK, s2 = INVK, s3 = INVK;

    for (int j = wave; j < total; j += NW) {
        int f = sList[j];                 // wave-uniform broadcast
        const float* fd = &sFD[f * 10];
        float a0x = fd[0], a0y = fd[1], a1x = fd[2], a1y = fd[3], a2x = fd[4], a2y = fd[5];
        float z0 = fd[6], z1 = fd[7], z2 = fd[8], denom = fd[9];
        float e0x = a2x - a1x, e0y = a2y - a1y;   // a1->a2
        float e1x = a0x - a2x, e1y = a0y - a2y;   // a2->a0
        float e2x = a1x - a0x, e2y = a1y - a0y;   // a0->a1
        float p0x = px - a0x, p0y = py - a0y;
        float p1x = px - a1x, p1y = py - a1y;
        float p2x = px - a2x, p2y = py - a2y;
        float w0 = p1x * e0y - p1y * e0x;
        float w1 = p2x * e1y - p2y * e1x;
        float w2 = p0x * e2y - p0y * e2x;
        float b0 = w0 / denom, b1 = w1 / denom, b2 = w2 / denom;  // IEEE divides
        float zpix = (b0 * z0 + b1 * z1) + b2 * z2;               // numpy order
        bool inside = fminf(b0, fminf(b1, b2)) >= 0.0f;           // no NaNs possible
        bool valid;
        if (__all(inside)) {
            valid = (zpix > EPSF);
        } else {
            float dA = seg_d2(p0x, p0y, e2x, e2y);   // (p,a0,a1)
            float dB = seg_d2(p1x, p1y, e0x, e0y);   // (p,a1,a2)
            float dC = seg_d2(p2x, p2y, e1x, e1y);   // (p,a2,a0)
            float dmin = fminf(dA, fminf(dB, dC));
            valid = (inside | (dmin < BLURF)) & (zpix > EPSF);
        }
        u64 key = valid ? ((((u64)__float_as_uint(zpix)) << 32) | (unsigned)f) : INVK;
        if (__any(key < s3)) ins4(s0, s1, s2, s3, key);
    }

    // ---------------- cross-wave tree merge (uint64 keys, 8-row ping-pong) ------
    for (int s = 8; s >= 1; s >>= 1) {
        if (wave >= s && wave < 2 * s) {
            int r = wave - s;
            sK[(r * 4 + 0) * 64 + lane] = s0;
            sK[(r * 4 + 1) * 64 + lane] = s1;
            sK[(r * 4 + 2) * 64 + lane] = s2;
            sK[(r * 4 + 3) * 64 + lane] = s3;
        }
        __syncthreads();
        if (wave < s) {
            u64 t0 = sK[(wave * 4 + 0) * 64 + lane];
            u64 t1 = sK[(wave * 4 + 1) * 64 + lane];
            u64 t2 = sK[(wave * 4 + 2) * 64 + lane];
            u64 t3 = sK[(wave * 4 + 3) * 64 + lane];
            ins4(s0, s1, s2, s3, t0);
            ins4(s0, s1, s2, s3, t1);
            ins4(s0, s1, s2, s3, t2);
            ins4(s0, s1, s2, s3, t3);
        }
        __syncthreads();
    }
    if (wave == 0) {
        sK[0 * 64 + lane] = s0;
        sK[1 * 64 + lane] = s1;
        sK[2 * 64 + lane] = s2;
        sK[3 * 64 + lane] = s3;
    }
    __syncthreads();

    // ---------------- phase 2: exact recompute for <=4 selected, write ----------
    if (tid < 256) {
        int pix = tid >> 2, k = tid & 3;
        u64 key = sK[k * 64 + pix];
        int prow = pix >> 3, pcol = pix & 7;
        int grow = trow * 8 + prow, gcol = tcol * 8 + pcol;
        int p = (b * IMG + grow) * IMG + gcol;
        float qx = 1.0f - (2.0f * ((float)gcol + 0.5f)) / 128.0f;
        float qy = 1.0f - (2.0f * ((float)grow + 0.5f)) / 128.0f;
        float o0 = -1.0f, o1 = -1.0f, ob0 = -1.0f, ob1 = -1.0f, ob2 = -1.0f, o3 = -1.0f;
        if ((unsigned)(key >> 32) != 0x7f800000u) {
            int fi = (int)(unsigned)(key & 0xffffffffu);
            const float* fd = &sFD[fi * 10];
            float a0x = fd[0], a0y = fd[1], a1x = fd[2], a1y = fd[3], a2x = fd[4], a2y = fd[5];
            float z0 = fd[6], z1 = fd[7], z2 = fd[8], denom = fd[9];
            float e0x = a2x - a1x, e0y = a2y - a1y;
            float e1x = a0x - a2x, e1y = a0y - a2y;
            float e2x = a1x - a0x, e2y = a1y - a0y;
            float p0x = qx - a0x, p0y = qy - a0y;
            float p1x = qx - a1x, p1y = qy - a1y;
            float p2x = qx - a2x, p2y = qy - a2y;
            float w0 = p1x * e0y - p1y * e0x;
            float w1 = p2x * e1y - p2y * e1x;
            float w2 = p0x * e2y - p0y * e2x;
            float b0 = w0 / denom, b1 = w1 / denom, b2 = w2 / denom;
            float zpix = (b0 * z0 + b1 * z1) + b2 * z2;
            bool inside = (b0 >= 0.0f) & (b1 >= 0.0f) & (b2 >= 0.0f);
            float dA = seg_d2(p0x, p0y, e2x, e2y);
            float dB = seg_d2(p1x, p1y, e0x, e0y);
            float dC = seg_d2(p2x, p2y, e1x, e1y);
            float dmin = fminf(dA, fminf(dB, dC));
            o0 = (float)fi;
            o1 = zpix;
            ob0 = b0; ob1 = b1; ob2 = b2;
            o3 = inside ? -dmin : dmin;
        }
        int o = p * KF + k;
        out0[o] = o0;
        out1[o] = o1;
        out2[o * 3 + 0] = ob0;
        out2[o * 3 + 1] = ob1;
        out2[o * 3 + 2] = ob2;
        out3[o] = o3;
    }
}

extern "C" void kernel_launch(void* const* d_in, const int* in_sizes, int n_in,
                              void* d_out, int out_size, void* d_ws, size_t ws_size,
                              hipStream_t stream) {
    const float* verts = (const float*)d_in[0];
    const int*   faces = (const int*)d_in[1];
    float* out = (float*)d_out;
    const int n0 = NB * IMG * IMG * KF;   // 131072 per (B,H,W,K) output
    // concat order: pix_to_face, zbuf, bary(3x), dsign
    raster_kernel<<<dim3(512), dim3(1024), 0, stream>>>(
        verts, faces,
        out,                 // [0, n0)
        out + n0,            // [n0, 2n0)
        out + 2 * n0,        // [2n0, 5n0)
        out + 5 * n0);       // [5n0, 6n0)
}

// Round 4
// 95.557 us; speedup vs baseline: 1.5085x; 1.1455x over previous
//
#include <hip/hip_runtime.h>

#define IMG   128
#define KF    4
#define NF    800
#define NV    2000
#define NB    2
#define EPSF  1e-8f
#define BLURF 0.01f
// rect-edge cull: dist>0.1015 => (w/len)^2 > 0.0103 with w<0
#define CULL_D2 0.0103f
#define HEXT    0.0547f   // tile half-extent (7/128) + margin

typedef unsigned long long u64;
#define INVK ((((u64)0x7f800000u) << 32) | 0xffffffffu)   // z=+inf, idx=-1

// Match numpy: no FMA contraction anywhere on the exact paths.
#pragma clang fp contract(off)

__device__ __forceinline__ float seg_d2(float pax, float pay, float abx, float aby) {
#pragma clang fp contract(off)
    float dd = (abx * abx + aby * aby) + EPSF;
    float t  = (pax * abx + pay * aby) / dd;   // true IEEE divide
    t = fminf(fmaxf(t, 0.0f), 1.0f);
    float dx = pax - t * abx;
    float dy = pay - t * aby;
    return dx * dx + dy * dy;
}

__device__ __forceinline__ void ins4(u64& s0, u64& s1, u64& s2, u64& s3, u64 k) {
    bool c0 = k < s0, c1 = k < s1, c2 = k < s2, c3 = k < s3;
    s3 = c2 ? s2 : (c3 ? k : s3);
    s2 = c1 ? s1 : (c2 ? k : s2);
    s1 = c0 ? s0 : (c1 ? k : s1);
    s0 = c0 ? k  : s0;
}

// ---------------- kernel 1: per (tile, face-slice) partial top-4 ----------------
__global__ __launch_bounds__(256) void raster_p1(
    const float* __restrict__ verts,   // (B, V, 3)
    const int*   __restrict__ faces,   // (F, 3)
    u64* __restrict__ ws,              // [512*S][4][64] partial keys
    int sh)                            // log2(slices)
{
#pragma clang fp contract(off)
    extern __shared__ char dynLDS[];   // fd[chunk*10] floats, then list[chunk] ints
    __shared__ u64 sK[2 * 4 * 64];     // merge rows (4 KB)
    __shared__ int sTot;

    const int S     = 1 << sh;
    const int chunk = NF >> sh;
    float* sFD  = (float*)dynLDS;
    int*   sList = (int*)(dynLDS + (size_t)chunk * 10 * sizeof(float));

    const int tid   = threadIdx.x;
    const int blk   = blockIdx.x;
    const int tile  = blk >> sh;
    const int slice = blk & (S - 1);
    const int b     = tile >> 8;
    const int trow  = (tile & 255) >> 4;
    const int tcol  = tile & 15;
    const float* vb = verts + b * NV * 3;
    const int fbase = slice * chunk;

    if (tid == 0) sTot = 0;

    // staging: this slice's faces -> LDS (local index j, global face = fbase+j)
    for (int j = tid; j < chunk; j += 256) {
        int f = fbase + j;
        int i0 = faces[3 * f + 0], i1 = faces[3 * f + 1], i2 = faces[3 * f + 2];
        float a0x = vb[3 * i0], a0y = vb[3 * i0 + 1], z0 = vb[3 * i0 + 2];
        float a1x = vb[3 * i1], a1y = vb[3 * i1 + 1], z1 = vb[3 * i1 + 2];
        float a2x = vb[3 * i2], a2y = vb[3 * i2 + 1], z2 = vb[3 * i2 + 2];
        // numpy op order for area (exact-match)
        float area = (a2x - a0x) * (a1y - a0y) - (a2y - a0y) * (a1x - a0x);
        float aab  = fabsf(area);
        float denom = (aab > EPSF) ? area : (area >= 0.0f ? EPSF : -EPSF);
        float* fd = &sFD[j * 10];
        fd[0] = a0x; fd[1] = a0y; fd[2] = a1x; fd[3] = a1y; fd[4] = a2x; fd[5] = a2y;
        fd[6] = z0;  fd[7] = z1;  fd[8] = z2;  fd[9] = denom;
    }
    __syncthreads();

    // tile geometry
    const int wave = tid >> 6;
    const int lane = tid & 63;
    const int pr = lane >> 3, pc = lane & 7;          // 8x8 tile
    const int row = trow * 8 + pr, col = tcol * 8 + pc;
    const float px = 1.0f - (2.0f * ((float)col + 0.5f)) / 128.0f;
    const float py = 1.0f - (2.0f * ((float)row + 0.5f)) / 128.0f;
    const float txmax = 1.0f - (2.0f * ((float)(tcol * 8)     + 0.5f)) / 128.0f;
    const float txmin = 1.0f - (2.0f * ((float)(tcol * 8 + 7) + 0.5f)) / 128.0f;
    const float tymax = 1.0f - (2.0f * ((float)(trow * 8)     + 0.5f)) / 128.0f;
    const float tymin = 1.0f - (2.0f * ((float)(trow * 8 + 7) + 0.5f)) / 128.0f;
    const float cx = 0.5f * (txmin + txmax);
    const float cy = 0.5f * (tymin + tymax);

    // cull -> unordered survivor list (order irrelevant: u64 keys)
    for (int j = tid; j < chunk; j += 256) {
        const float* fd = &sFD[j * 10];
        float a0x = fd[0], a0y = fd[1], a1x = fd[2], a1y = fd[3], a2x = fd[4], a2y = fd[5];
        float area = (a2x - a0x) * (a1y - a0y) - (a2y - a0y) * (a1x - a0x);
        bool surv = fabsf(area) > EPSF;
        float bxmin = fminf(a0x, fminf(a1x, a2x)) - 0.101f;
        float bxmax = fmaxf(a0x, fmaxf(a1x, a2x)) + 0.101f;
        float bymin = fminf(a0y, fminf(a1y, a2y)) - 0.101f;
        float bymax = fmaxf(a0y, fmaxf(a1y, a2y)) + 0.101f;
        surv &= !(bxmin > txmax || bxmax < txmin || bymin > tymax || bymax < tymin);
        // exact rect-vs-edge-line cull: max over rect of signed insideness < -0.1015*len
        float s = (area >= 0.0f) ? 1.0f : -1.0f;
        float e0x = a2x - a1x, e0y = a2y - a1y;
        float e1x = a0x - a2x, e1y = a0y - a2y;
        float e2x = a1x - a0x, e2y = a1y - a0y;
        float w0 = s * ((cx - a1x) * e0y - (cy - a1y) * e0x) + HEXT * (fabsf(e0x) + fabsf(e0y));
        float w1 = s * ((cx - a2x) * e1y - (cy - a2y) * e1x) + HEXT * (fabsf(e1x) + fabsf(e1y));
        float w2 = s * ((cx - a0x) * e2y - (cy - a0y) * e2x) + HEXT * (fabsf(e2x) + fabsf(e2y));
        float l0 = e0x * e0x + e0y * e0y;
        float l1 = e1x * e1x + e1y * e1y;
        float l2 = e2x * e2x + e2y * e2y;
        surv &= !((w0 < 0.0f) & (w0 * w0 > CULL_D2 * l0));
        surv &= !((w1 < 0.0f) & (w1 * w1 > CULL_D2 * l1));
        surv &= !((w2 < 0.0f) & (w2 * w2 > CULL_D2 * l2));
        if (surv) {
            int pos = atomicAdd(&sTot, 1);
            sList[pos] = j;
        }
    }
    __syncthreads();
    const int total = sTot;

    // phase 1: 4 waves stride the survivor list; per-lane(-pixel) top-4 keys
    u64 s0 = INVK, s1 = INVK, s2 = INVK, s3 = INVK;
    for (int j = wave; j < total; j += 4) {
        int lf = sList[j];                 // wave-uniform broadcast
        const float* fd = &sFD[lf * 10];
        float a0x = fd[0], a0y = fd[1], a1x = fd[2], a1y = fd[3], a2x = fd[4], a2y = fd[5];
        float z0 = fd[6], z1 = fd[7], z2 = fd[8], denom = fd[9];
        float e0x = a2x - a1x, e0y = a2y - a1y;   // a1->a2
        float e1x = a0x - a2x, e1y = a0y - a2y;   // a2->a0
        float e2x = a1x - a0x, e2y = a1y - a0y;   // a0->a1
        float p0x = px - a0x, p0y = py - a0y;
        float p1x = px - a1x, p1y = py - a1y;
        float p2x = px - a2x, p2y = py - a2y;
        float w0 = p1x * e0y - p1y * e0x;
        float w1 = p2x * e1y - p2y * e1x;
        float w2 = p0x * e2y - p0y * e2x;
        float b0 = w0 / denom, b1 = w1 / denom, b2 = w2 / denom;  // IEEE divides
        float zpix = (b0 * z0 + b1 * z1) + b2 * z2;               // numpy order
        bool inside = fminf(b0, fminf(b1, b2)) >= 0.0f;           // no NaNs possible
        bool valid;
        if (__all(inside)) {
            valid = (zpix > EPSF);
        } else {
            float dA = seg_d2(p0x, p0y, e2x, e2y);   // (p,a0,a1)
            float dB = seg_d2(p1x, p1y, e0x, e0y);   // (p,a1,a2)
            float dC = seg_d2(p2x, p2y, e1x, e1y);   // (p,a2,a0)
            float dmin = fminf(dA, fminf(dB, dC));
            valid = (inside | (dmin < BLURF)) & (zpix > EPSF);
        }
        u64 key = valid ? ((((u64)__float_as_uint(zpix)) << 32) | (unsigned)(fbase + lf)) : INVK;
        if (__any(key < s3)) ins4(s0, s1, s2, s3, key);
    }

    // cross-wave merge: 4 waves -> wave 0
    if (wave >= 2) {
        int r = wave - 2;
        sK[(r * 4 + 0) * 64 + lane] = s0;
        sK[(r * 4 + 1) * 64 + lane] = s1;
        sK[(r * 4 + 2) * 64 + lane] = s2;
        sK[(r * 4 + 3) * 64 + lane] = s3;
    }
    __syncthreads();
    if (wave < 2) {
        ins4(s0, s1, s2, s3, sK[(wave * 4 + 0) * 64 + lane]);
        ins4(s0, s1, s2, s3, sK[(wave * 4 + 1) * 64 + lane]);
        ins4(s0, s1, s2, s3, sK[(wave * 4 + 2) * 64 + lane]);
        ins4(s0, s1, s2, s3, sK[(wave * 4 + 3) * 64 + lane]);
    }
    __syncthreads();
    if (wave == 1) {
        sK[0 * 64 + lane] = s0;
        sK[1 * 64 + lane] = s1;
        sK[2 * 64 + lane] = s2;
        sK[3 * 64 + lane] = s3;
    }
    __syncthreads();
    if (wave == 0) {
        ins4(s0, s1, s2, s3, sK[0 * 64 + lane]);
        ins4(s0, s1, s2, s3, sK[1 * 64 + lane]);
        ins4(s0, s1, s2, s3, sK[2 * 64 + lane]);
        ins4(s0, s1, s2, s3, sK[3 * 64 + lane]);
        u64* wrow = ws + (size_t)blk * 256;
        wrow[0 * 64 + lane] = s0;
        wrow[1 * 64 + lane] = s1;
        wrow[2 * 64 + lane] = s2;
        wrow[3 * 64 + lane] = s3;
    }
}

// ---------------- kernel 2: merge slices + exact epilogue ----------------
__global__ __launch_bounds__(256) void raster_p2(
    const float* __restrict__ verts,
    const int*   __restrict__ faces,
    const u64* __restrict__ ws,
    int sh,
    float* __restrict__ out0, float* __restrict__ out1,
    float* __restrict__ out2, float* __restrict__ out3)
{
#pragma clang fp contract(off)
    __shared__ u64 sK[4 * 64];
    const int S    = 1 << sh;
    const int tid  = threadIdx.x;
    const int tile = blockIdx.x;
    const int b    = tile >> 8;
    const int trow = (tile & 255) >> 4;
    const int tcol = tile & 15;
    const float* vb = verts + b * NV * 3;

    if (tid < 64) {
        u64 s0 = INVK, s1 = INVK, s2 = INVK, s3 = INVK;
        const u64* base = ws + (size_t)tile * S * 256;
        for (int s = 0; s < S; ++s) {
            ins4(s0, s1, s2, s3, base[s * 256 + 0 * 64 + tid]);
            ins4(s0, s1, s2, s3, base[s * 256 + 1 * 64 + tid]);
            ins4(s0, s1, s2, s3, base[s * 256 + 2 * 64 + tid]);
            ins4(s0, s1, s2, s3, base[s * 256 + 3 * 64 + tid]);
        }
        sK[0 * 64 + tid] = s0;
        sK[1 * 64 + tid] = s1;
        sK[2 * 64 + tid] = s2;
        sK[3 * 64 + tid] = s3;
    }
    __syncthreads();

    int pix = tid >> 2, k = tid & 3;
    u64 key = sK[k * 64 + pix];
    int prow = pix >> 3, pcol = pix & 7;
    int grow = trow * 8 + prow, gcol = tcol * 8 + pcol;
    int p = (b * IMG + grow) * IMG + gcol;
    float qx = 1.0f - (2.0f * ((float)gcol + 0.5f)) / 128.0f;
    float qy = 1.0f - (2.0f * ((float)grow + 0.5f)) / 128.0f;
    float o0 = -1.0f, o1 = -1.0f, ob0 = -1.0f, ob1 = -1.0f, ob2 = -1.0f, o3 = -1.0f;
    if ((unsigned)(key >> 32) != 0x7f800000u) {
        int fi = (int)(unsigned)(key & 0xffffffffu);
        int i0 = faces[3 * fi + 0], i1 = faces[3 * fi + 1], i2 = faces[3 * fi + 2];
        float a0x = vb[3 * i0], a0y = vb[3 * i0 + 1], z0 = vb[3 * i0 + 2];
        float a1x = vb[3 * i1], a1y = vb[3 * i1 + 1], z1 = vb[3 * i1 + 2];
        float a2x = vb[3 * i2], a2y = vb[3 * i2 + 1], z2 = vb[3 * i2 + 2];
        float area = (a2x - a0x) * (a1y - a0y) - (a2y - a0y) * (a1x - a0x);
        float aab  = fabsf(area);
        float denom = (aab > EPSF) ? area : (area >= 0.0f ? EPSF : -EPSF);
        float e0x = a2x - a1x, e0y = a2y - a1y;
        float e1x = a0x - a2x, e1y = a0y - a2y;
        float e2x = a1x - a0x, e2y = a1y - a0y;
        float p0x = qx - a0x, p0y = qy - a0y;
        float p1x = qx - a1x, p1y = qy - a1y;
        float p2x = qx - a2x, p2y = qy - a2y;
        float w0 = p1x * e0y - p1y * e0x;
        float w1 = p2x * e1y - p2y * e1x;
        float w2 = p0x * e2y - p0y * e2x;
        float b0 = w0 / denom, b1 = w1 / denom, b2 = w2 / denom;
        float zpix = (b0 * z0 + b1 * z1) + b2 * z2;
        bool inside = (b0 >= 0.0f) & (b1 >= 0.0f) & (b2 >= 0.0f);
        float dA = seg_d2(p0x, p0y, e2x, e2y);
        float dB = seg_d2(p1x, p1y, e0x, e0y);
        float dC = seg_d2(p2x, p2y, e1x, e1y);
        float dmin = fminf(dA, fminf(dB, dC));
        o0 = (float)fi;
        o1 = zpix;
        ob0 = b0; ob1 = b1; ob2 = b2;
        o3 = inside ? -dmin : dmin;
    }
    int o = p * KF + k;
    out0[o] = o0;
    out1[o] = o1;
    out2[o * 3 + 0] = ob0;
    out2[o * 3 + 1] = ob1;
    out2[o * 3 + 2] = ob2;
    out3[o] = o3;
}

extern "C" void kernel_launch(void* const* d_in, const int* in_sizes, int n_in,
                              void* d_out, int out_size, void* d_ws, size_t ws_size,
                              hipStream_t stream) {
    const float* verts = (const float*)d_in[0];
    const int*   faces = (const int*)d_in[1];
    float* out = (float*)d_out;
    const int n0 = NB * IMG * IMG * KF;   // 131072 per (B,H,W,K) output

    const size_t per_slice = 512ull * 256 * sizeof(u64);   // 1 MB
    int sh;
    if      (ws_size >= 4 * per_slice) sh = 2;   // 4 slices
    else if (ws_size >= 2 * per_slice) sh = 1;   // 2 slices
    else                               sh = 0;   // 1 slice
    const int S = 1 << sh;
    const int chunk = NF >> sh;
    const size_t dyn = (size_t)chunk * 10 * sizeof(float) + (size_t)chunk * sizeof(int);

    raster_p1<<<dim3(512 * S), dim3(256), dyn, stream>>>(verts, faces, (u64*)d_ws, sh);
    raster_p2<<<dim3(512), dim3(256), 0, stream>>>(verts, faces, (const u64*)d_ws, sh,
        out,                 // pix_to_face
        out + n0,            // zbuf
        out + 2 * n0,        // bary
        out + 5 * n0);       // dsign
}